// Round 17
// baseline (86.278 us; speedup 1.0000x reference)
//
#include <hip/hip_runtime.h>
#include <hip/hip_bf16.h>
#include <stdint.h>

typedef __attribute__((ext_vector_type(8))) short short8;
typedef __attribute__((ext_vector_type(4))) float f32x4;

#define NB 128
#define NL 256
#define NROWS 32768        // B*L
#define IN_DIM 360
#define KP1 384            // padded K for layer-1 GEMM (permuted layout)
#define MEM 200
#define NP 256             // padded N
#define OUT_X (NROWS * MEM)
#define YTP 264            // Yt pitch in bf16 (528 B rows)
#define BUFSZ 20480        // one staging buffer: At 16K + Bt 4K
#define YTOFF 40960        // Yt offset in smem

// Permuted K layout for x/W0p (keeps every 8-col chunk single-table):
//   kp 0..299 emb | kp 304..333 pos | kp 336..365 ner | else zero
// Chunk id c = kp/8: 0..36 emb-full | 37 emb-tail | 38..41 pos | 42..45 ner | 46,47 zero

__device__ __forceinline__ unsigned short f2b(float f) {
    unsigned u = __builtin_bit_cast(unsigned, f);
    unsigned r = (u + 0x7FFFu + ((u >> 16) & 1u)) >> 16;
    return (unsigned short)r;
}

// gather one 8-col chunk of the (permuted) embedding row as bf16
__device__ __forceinline__ short8 gather_chunk(int chunk, const float* __restrict__ er,
                                               const float* __restrict__ pr,
                                               const float* __restrict__ nr) {
    float v[8];
    if (chunk < 37) {                                   // emb, 16B-aligned (stride 1200 B)
        const float* s = er + chunk * 8;
        float4 a = *(const float4*)s;
        float4 b = *(const float4*)(s + 4);
        v[0] = a.x; v[1] = a.y; v[2] = a.z; v[3] = a.w;
        v[4] = b.x; v[5] = b.y; v[6] = b.z; v[7] = b.w;
    } else if (chunk == 37) {                           // emb tail 296..299 + pad
        float4 a = *(const float4*)(er + 296);
        v[0] = a.x; v[1] = a.y; v[2] = a.z; v[3] = a.w;
        v[4] = 0.f; v[5] = 0.f; v[6] = 0.f; v[7] = 0.f;
    } else if (chunk <= 41) {                           // pos (stride 120 B: scalar, guarded)
        int k0 = chunk * 8 - 304;
        #pragma unroll
        for (int i = 0; i < 8; ++i) v[i] = (k0 + i < 30) ? pr[k0 + i] : 0.f;
    } else if (chunk <= 45) {                           // ner
        int k0 = chunk * 8 - 336;
        #pragma unroll
        for (int i = 0; i < 8; ++i) v[i] = (k0 + i < 30) ? nr[k0 + i] : 0.f;
    } else {
        #pragma unroll
        for (int i = 0; i < 8; ++i) v[i] = 0.f;
    }
    short8 r;
    #pragma unroll
    for (int i = 0; i < 8; ++i) r[i] = (short)f2b(v[i]);
    return r;
}

// ---------------- weight prep + colnz zero
__global__ void prep_weights(const float* __restrict__ W0, const float* __restrict__ W1,
                             short* __restrict__ W0p, short* __restrict__ W1p,
                             unsigned* __restrict__ colnz) {
    int idx = blockIdx.x * 256 + threadIdx.x;
    if (idx < NROWS) colnz[idx] = 0u;
    if (idx < NP * KP1) {
        int n = idx / KP1, kp = idx - n * KP1;
        float v = 0.f;
        if (n < MEM) {
            if (kp < 300)                   v = W0[n * IN_DIM + kp];
            else if (kp >= 304 && kp < 334) v = W0[n * IN_DIM + 300 + (kp - 304)];
            else if (kp >= 336 && kp < 366) v = W0[n * IN_DIM + 330 + (kp - 336)];
        }
        W0p[idx] = (short)f2b(v);
    } else {
        int i2 = idx - NP * KP1;
        if (i2 < NP * NP) {
            int n = i2 >> 8, k = i2 & 255;
            float v = (n < MEM && k < MEM) ? W1[n * MEM + k] : 0.f;
            W1p[i2] = (short)f2b(v);
        }
    }
}

// ---------------- adj row pass: rowsum/dinv, S = (A+I) bf16 [B][256][256], colnz flags
__global__ void adjrow_kernel(const float* __restrict__ adj, float* __restrict__ dinv,
                              float* __restrict__ rsum, unsigned short* __restrict__ Sbf,
                              unsigned* __restrict__ colnz) {
    int row = blockIdx.x * 4 + (threadIdx.x >> 6);
    int lane = threadIdx.x & 63;
    const float4* ar = (const float4*)(adj + (size_t)row * NL);
    float4 v = ar[lane];
    float s = v.x + v.y + v.z + v.w;
    #pragma unroll
    for (int off = 32; off >= 1; off >>= 1) s += __shfl_xor(s, off);
    int rloc = row & 255;
    float d0 = v.x + ((lane * 4 + 0) == rloc ? 1.f : 0.f);
    float d1 = v.y + ((lane * 4 + 1) == rloc ? 1.f : 0.f);
    float d2 = v.z + ((lane * 4 + 2) == rloc ? 1.f : 0.f);
    float d3 = v.w + ((lane * 4 + 3) == rloc ? 1.f : 0.f);
    ushort4 st; st.x = f2b(d0); st.y = f2b(d1); st.z = f2b(d2); st.w = f2b(d3);
    *(ushort4*)(Sbf + (size_t)row * NL + lane * 4) = st;
    if (lane == 0) { rsum[row] = s; dinv[row] = 1.0f / (s + 1.0f); }
    unsigned* cz = colnz + ((row >> 8) << 8);
    if (v.x != 0.f) atomicOr(&cz[lane * 4 + 0], 1u);
    if (v.y != 0.f) atomicOr(&cz[lane * 4 + 1], 1u);
    if (v.z != 0.f) atomicOr(&cz[lane * 4 + 2], 1u);
    if (v.w != 0.f) atomicOr(&cz[lane * 4 + 3], 1u);
}

// ---------------- FUSED per-layer, all-MFMA, double-buffered LDS, 3-DEEP A/B pipeline.
// Two register sets (P=even tiles, Q=odd tiles), loop unrolled x2 with static parity:
// load for tile kt+3 issues at step kt -> ~2 steps (~1600 cyc) of global-latency cover.
// FINAL=0: A-tile staging IS the embedding gather; also writes mask (folded mask_kernel).
// N-slice 64 (grid 512 = 2 blocks/CU); 8 waves 4x2, wave tile 64x32, acc[4][2].
template <int FINAL>
__global__ __launch_bounds__(512, 4) void fused_kernel(
    const short* __restrict__ A, int lda, int nkt,
    const short* __restrict__ Bp, int ldb,
    const unsigned short* __restrict__ Sbf,
    const float* __restrict__ dinv, const float* __restrict__ bias,
    const int* __restrict__ words, const int* __restrict__ pos, const int* __restrict__ ner,
    const float* __restrict__ embW, const float* __restrict__ posW,
    const float* __restrict__ nerW,
    const float* __restrict__ rsum, const unsigned* __restrict__ colnz,
    float* __restrict__ maskout,
    short* __restrict__ x1b, float* __restrict__ outx) {
    extern __shared__ char smem[];
    unsigned short* Yt = (unsigned short*)(smem + YTOFF);   // [64][YTP] bf16

    int bi = blockIdx.x;
    int batch = bi & 127, sl = bi >> 7;                 // 4 slices of a batch -> same XCD

    int tid = threadIdx.x;
    int lane = tid & 63, wid = tid >> 6;
    int wr = wid >> 1, wc = wid & 1;                    // 4 x 2 wave grid
    int lr = lane & 15, lc = lane >> 4;

    // folded mask_kernel (FINAL=0, slice-0 blocks; adjrow outputs ready at launch)
    if (FINAL == 0 && sl == 0 && tid < 256) {
        int r = batch * NL + tid;
        maskout[r] = (rsum[r] == 0.f && colnz[r] == 0u) ? 1.0f : 0.0f;
    }

    const short* Bb = Bp + (size_t)sl * 64 * ldb;
    const short* Sb = (const short*)(Sbf + (size_t)batch * NL * NL);

    // staging slots (byte offsets within a buffer)
    int r0s = tid >> 2, c0s = tid & 3;
    int r1s = r0s + 128;
    int offA0 = r0s * 64 + (c0s ^ ((r0s >> 1) & 3)) * 16;
    int offA1 = r1s * 64 + (c0s ^ ((r1s >> 1) & 3)) * 16;
    const short* Sp0 = Sb + (size_t)r0s * NL + c0s * 8;
    const short* Sp1 = Sb + (size_t)r1s * NL + c0s * 8;
    int offB = 0; const short* Bpp = nullptr;
    if (tid < 256) {
        int br = tid >> 2, bc = tid & 3;
        offB = 16384 + br * 64 + (bc ^ ((br >> 1) & 3)) * 16;
        Bpp = Bb + (size_t)br * ldb + bc * 8;
    }

    // A source: FINAL=0 -> per-row table pointers; FINAL=1 -> X1b pointers
    const short* Ap0 = nullptr; const short* Ap1 = nullptr;
    const float *er0 = nullptr, *pr0 = nullptr, *nr0 = nullptr;
    const float *er1 = nullptr, *pr1 = nullptr, *nr1 = nullptr;
    if (FINAL == 0) {
        int g0 = batch * NL + r0s, g1 = g0 + 128;
        er0 = embW + (size_t)words[g0] * 300;
        pr0 = posW + (size_t)pos[g0] * 30;
        nr0 = nerW + (size_t)ner[g0] * 30;
        er1 = embW + (size_t)words[g1] * 300;
        pr1 = posW + (size_t)pos[g1] * 30;
        nr1 = nerW + (size_t)ner[g1] * 30;
    } else {
        const short* Ab = A + (size_t)batch * NL * lda;
        Ap0 = Ab + (size_t)r0s * lda + c0s * 8;
        Ap1 = Ab + (size_t)r1s * lda + c0s * 8;
    }
    #define LOADA(kt, o0, o1) do {                                  \
        if (FINAL == 0) {                                           \
            int ch_ = (kt) * 4 + c0s;                               \
            (o0) = gather_chunk(ch_, er0, pr0, nr0);                \
            (o1) = gather_chunk(ch_, er1, pr1, nr1);                \
        } else {                                                    \
            (o0) = *(const short8*)(Ap0 + (kt) * 32);               \
            (o1) = *(const short8*)(Ap1 + (kt) * 32);               \
        }                                                           \
    } while (0)

    f32x4 acc[4][2] = {};
    short8 sA0, sA1, sB0, sB1;                          // S t0/t1 regs (phase 2b prologue)

    // two register sets: P holds even tiles, Q holds odd tiles
    short8 aP0, aP1, bP, aQ0, aQ1, bQ;
    // prologue: tile 0 -> buf0 directly; tile 1 -> Q; tile 2 -> P
    LOADA(0, aP0, aP1);
    if (tid < 256) bP = *(const short8*)Bpp;
    *(short8*)(smem + offA0) = aP0;
    *(short8*)(smem + offA1) = aP1;
    if (tid < 256) *(short8*)(smem + offB) = bP;
    LOADA(1, aQ0, aQ1);
    if (tid < 256) bQ = *(const short8*)(Bpp + 32);
    LOADA(2, aP0, aP1);
    if (tid < 256) bP = *(const short8*)(Bpp + 64);
    __syncthreads();

    // STEP1(kt, P=kt&1, S* = set holding tile kt+1 / receiving tile kt+3)
    #define STEP1(kt, PAR, SA0, SA1, SB) do {                                   \
        char* base_ = smem + (PAR) * BUFSZ;                                     \
        short8 af[4], bf[2];                                                    \
        _Pragma("unroll")                                                       \
        for (int mi = 0; mi < 4; ++mi) {                                        \
            int row = wr * 64 + mi * 16 + lr;                                   \
            int cs = lc ^ ((row >> 1) & 3);                                     \
            af[mi] = *(const short8*)(base_ + row * 64 + cs * 16);              \
        }                                                                       \
        _Pragma("unroll")                                                       \
        for (int ni = 0; ni < 2; ++ni) {                                        \
            int row = wc * 32 + ni * 16 + lr;                                   \
            int cs = lc ^ ((row >> 1) & 3);                                     \
            bf[ni] = *(const short8*)(base_ + 16384 + row * 64 + cs * 16);      \
        }                                                                       \
        if ((kt) + 1 < nkt) {                                                   \
            char* nb_ = smem + (1 - (PAR)) * BUFSZ;                             \
            *(short8*)(nb_ + offA0) = SA0;                                      \
            *(short8*)(nb_ + offA1) = SA1;                                      \
            if (tid < 256) *(short8*)(nb_ + offB) = SB;                         \
        }                                                                       \
        if ((kt) + 3 < nkt) {                                                   \
            LOADA((kt) + 3, SA0, SA1);                                          \
            if (tid < 256) SB = *(const short8*)(Bpp + ((kt) + 3) * 32);        \
        } else if ((kt) + 3 == nkt) {                                           \
            sA0 = *(const short8*)Sp0;                                          \
            sA1 = *(const short8*)Sp1;                                          \
        } else if ((kt) + 3 == nkt + 1) {                                       \
            sB0 = *(const short8*)(Sp0 + 32);                                   \
            sB1 = *(const short8*)(Sp1 + 32);                                   \
        }                                                                       \
        _Pragma("unroll")                                                       \
        for (int mi = 0; mi < 4; ++mi) {                                        \
            acc[mi][0] = __builtin_amdgcn_mfma_f32_16x16x32_bf16(af[mi], bf[0], acc[mi][0], 0, 0, 0); \
            acc[mi][1] = __builtin_amdgcn_mfma_f32_16x16x32_bf16(af[mi], bf[1], acc[mi][1], 0, 0, 0); \
        }                                                                       \
        __syncthreads();                                                        \
    } while (0)

    for (int kb = 0; kb < nkt; kb += 2) {               // nkt is 12 or 8: even
        STEP1(kb + 0, 0, aQ0, aQ1, bQ);                 // even step: writes/loads odd set
        STEP1(kb + 1, 1, aP0, aP1, bP);                 // odd step: writes/loads even set
    }
    #undef STEP1
    #undef LOADA

    // Phase 2a: acc -> Yt transposed (col = y-col, 4 consecutive batch rows per 8B write)
    #pragma unroll
    for (int mi = 0; mi < 4; ++mi)
        #pragma unroll
        for (int ni = 0; ni < 2; ++ni) {
            f32x4 v = acc[mi][ni];
            ushort4 st; st.x = f2b(v[0]); st.y = f2b(v[1]); st.z = f2b(v[2]); st.w = f2b(v[3]);
            int col = wc * 32 + ni * 16 + lr;
            int row0 = wr * 64 + mi * 16 + lc * 4;
            *(ushort4*)(Yt + (size_t)col * YTP + row0) = st;
        }
    // stage S t0 -> buf0.At (buf0 free after final barrier); prefetch t2
    *(short8*)(smem + offA0) = sA0;
    *(short8*)(smem + offA1) = sA1;
    sA0 = *(const short8*)(Sp0 + 64);
    sA1 = *(const short8*)(Sp1 + 64);
    __syncthreads();                                    // Yt + S t0 visible

    // Phase 2b: Zt = Yt x S, 8 K-tiles, ping-pong staging, 1 barrier/tile
    f32x4 acc2[4][2] = {};
    #pragma unroll
    for (int kt = 0; kt < 8; ++kt) {
        char* base_ = smem + (kt & 1) * BUFSZ;
        short8 ay[4], bs[2];
        #pragma unroll
        for (int mi = 0; mi < 4; ++mi)                  // a = Y^T rows (y-cols), k-contig
            ay[mi] = *(const short8*)(Yt + (size_t)(mi * 16 + lr) * YTP + kt * 32 + lc * 8);
        #pragma unroll
        for (int ni = 0; ni < 2; ++ni) {                // b = S rows (out-rows), swizzled
            int row = wid * 32 + ni * 16 + lr;
            int cs = lc ^ ((row >> 1) & 3);
            bs[ni] = *(const short8*)(base_ + row * 64 + cs * 16);
        }
        if (kt + 1 < 8) {                               // write tile kt+1; reload that set
            char* nb_ = smem + ((kt + 1) & 1) * BUFSZ;
            if ((kt & 1) == 0) {
                *(short8*)(nb_ + offA0) = sB0;
                *(short8*)(nb_ + offA1) = sB1;
                if (kt + 3 < 8) {
                    sB0 = *(const short8*)(Sp0 + (kt + 3) * 32);
                    sB1 = *(const short8*)(Sp1 + (kt + 3) * 32);
                }
            } else {
                *(short8*)(nb_ + offA0) = sA0;
                *(short8*)(nb_ + offA1) = sA1;
                if (kt + 3 < 8) {
                    sA0 = *(const short8*)(Sp0 + (kt + 3) * 32);
                    sA1 = *(const short8*)(Sp1 + (kt + 3) * 32);
                }
            }
        }
        #pragma unroll
        for (int mi = 0; mi < 4; ++mi)
            #pragma unroll
            for (int ni = 0; ni < 2; ++ni)
                acc2[mi][ni] = __builtin_amdgcn_mfma_f32_16x16x32_bf16(ay[mi], bs[ni], acc2[mi][ni], 0, 0, 0);
        if (kt + 1 < 8) __syncthreads();
    }

    // Epilogue: lane holds outrow lr (fixed) x 4 consecutive y-cols per frag
    #pragma unroll
    for (int ni = 0; ni < 2; ++ni) {
        int g = batch * NL + wid * 32 + ni * 16 + lr;   // global output row
        float di = dinv[g];
        #pragma unroll
        for (int mi = 0; mi < 4; ++mi) {
            int col0 = sl * 64 + mi * 16 + lc * 4;      // global col (multiple of 4)
            float4 bv;
            if (col0 < MEM) bv = *(const float4*)(bias + col0);
            else { bv.x = 0.f; bv.y = 0.f; bv.z = 0.f; bv.w = 0.f; }
            f32x4 z = acc2[mi][ni];
            float h0 = fmaxf((z[0] + 2.f * bv.x) * di, 0.f);
            float h1 = fmaxf((z[1] + 2.f * bv.y) * di, 0.f);
            float h2 = fmaxf((z[2] + 2.f * bv.z) * di, 0.f);
            float h3 = fmaxf((z[3] + 2.f * bv.w) * di, 0.f);
            if (FINAL == 0) {
                ushort4 st; st.x = f2b(h0); st.y = f2b(h1); st.z = f2b(h2); st.w = f2b(h3);
                *(ushort4*)((unsigned short*)x1b + (size_t)g * NP + col0) = st;
            } else if (col0 < MEM) {
                float4 o; o.x = h0; o.y = h1; o.z = h2; o.w = h3;
                *(float4*)(outx + (size_t)g * MEM + col0) = o;
            }
        }
    }
}

extern "C" void kernel_launch(void* const* d_in, const int* in_sizes, int n_in,
                              void* d_out, int out_size, void* d_ws, size_t ws_size,
                              hipStream_t stream) {
    const int*   words = (const int*)d_in[0];
    const int*   pos   = (const int*)d_in[1];
    const int*   ner   = (const int*)d_in[2];
    const float* adj   = (const float*)d_in[3];
    const float* embW  = (const float*)d_in[4];
    const float* posW  = (const float*)d_in[5];
    const float* nerW  = (const float*)d_in[6];
    const float* W0    = (const float*)d_in[7];
    const float* b0    = (const float*)d_in[8];
    const float* W1    = (const float*)d_in[9];
    const float* b1    = (const float*)d_in[10];
    float* out = (float*)d_out;

    char* ws = (char*)d_ws;
    size_t off = 0;
    short* W0p = (short*)(ws + off);        off += (size_t)NP * KP1 * 2;
    short* W1p = (short*)(ws + off);        off += (size_t)NP * NP * 2;
    short* X1b = (short*)(ws + off);        off += (size_t)NROWS * NP * 2;        // 16.8 MB
    float* dinv = (float*)(ws + off);       off += (size_t)NROWS * 4;
    float* rsum = (float*)(ws + off);       off += (size_t)NROWS * 4;
    unsigned* colnz = (unsigned*)(ws + off); off += (size_t)NROWS * 4;
    unsigned short* Sbf = (unsigned short*)(ws + off); off += (size_t)NROWS * NL * 2; // 16.8 MB

    prep_weights<<<(NP * KP1 + NP * NP + 255) / 256, 256, 0, stream>>>(W0, W1, W0p, W1p, colnz);
    adjrow_kernel<<<NROWS / 4, 256, 0, stream>>>(adj, dinv, rsum, Sbf, colnz);

    const int ldsB = YTOFF + 64 * YTP * 2;   // 74,752 B
    fused_kernel<0><<<NB * 4, 512, ldsB, stream>>>(nullptr, KP1, KP1 / 32, W0p, KP1,
                                                   Sbf, dinv, b0,
                                                   words, pos, ner, embW, posW, nerW,
                                                   rsum, colnz, out + OUT_X,
                                                   X1b, nullptr);
    fused_kernel<1><<<NB * 4, 512, ldsB, stream>>>(X1b, NP, NP / 32, W1p, NP,
                                                   Sbf, dinv, b1,
                                                   nullptr, nullptr, nullptr, nullptr, nullptr, nullptr,
                                                   nullptr, nullptr, nullptr,
                                                   nullptr, out);
}

// Round 18
// 81.291 us; speedup vs baseline: 1.0614x; 1.0614x over previous
//
#include <hip/hip_runtime.h>
#include <hip/hip_bf16.h>
#include <stdint.h>

typedef __attribute__((ext_vector_type(8))) short short8;
typedef __attribute__((ext_vector_type(4))) float f32x4;

#define NB 128
#define NL 256
#define NROWS 32768        // B*L
#define IN_DIM 360
#define KP1 384            // padded K for layer-1 GEMM (permuted layout)
#define MEM 200
#define NP 256             // padded N
#define OUT_X (NROWS * MEM)
#define YTP 264            // Yt pitch in bf16 (528 B rows)
#define BUFSZ 20480        // one staging buffer: At 16K + Bt 4K
#define YTOFF 40960        // Yt offset in smem

// Permuted K layout for x/W0p (keeps every 8-col chunk single-table):
//   kp 0..299 emb | kp 304..333 pos | kp 336..365 ner | else zero
// Chunk id c = kp/8: 0..36 emb-full | 37 emb-tail | 38..41 pos | 42..45 ner | 46,47 zero

__device__ __forceinline__ unsigned short f2b(float f) {
    unsigned u = __builtin_bit_cast(unsigned, f);
    unsigned r = (u + 0x7FFFu + ((u >> 16) & 1u)) >> 16;
    return (unsigned short)r;
}

__device__ __forceinline__ void gl16(const void* g, void* l) {
    __builtin_amdgcn_global_load_lds((const __attribute__((address_space(1))) unsigned*)g,
                                     (__attribute__((address_space(3))) unsigned*)l, 16, 0, 0);
}

// gather one 8-col chunk of the (permuted) embedding row as bf16
__device__ __forceinline__ short8 gather_chunk(int chunk, const float* __restrict__ er,
                                               const float* __restrict__ pr,
                                               const float* __restrict__ nr) {
    float v[8];
    if (chunk < 37) {                                   // emb, 16B-aligned (stride 1200 B)
        const float* s = er + chunk * 8;
        float4 a = *(const float4*)s;
        float4 b = *(const float4*)(s + 4);
        v[0] = a.x; v[1] = a.y; v[2] = a.z; v[3] = a.w;
        v[4] = b.x; v[5] = b.y; v[6] = b.z; v[7] = b.w;
    } else if (chunk == 37) {                           // emb tail 296..299 + pad
        float4 a = *(const float4*)(er + 296);
        v[0] = a.x; v[1] = a.y; v[2] = a.z; v[3] = a.w;
        v[4] = 0.f; v[5] = 0.f; v[6] = 0.f; v[7] = 0.f;
    } else if (chunk <= 41) {                           // pos (stride 120 B: scalar, guarded)
        int k0 = chunk * 8 - 304;
        #pragma unroll
        for (int i = 0; i < 8; ++i) v[i] = (k0 + i < 30) ? pr[k0 + i] : 0.f;
    } else if (chunk <= 45) {                           // ner
        int k0 = chunk * 8 - 336;
        #pragma unroll
        for (int i = 0; i < 8; ++i) v[i] = (k0 + i < 30) ? nr[k0 + i] : 0.f;
    } else {
        #pragma unroll
        for (int i = 0; i < 8; ++i) v[i] = 0.f;
    }
    short8 r;
    #pragma unroll
    for (int i = 0; i < 8; ++i) r[i] = (short)f2b(v[i]);
    return r;
}

// ---------------- weight prep + colnz zero
__global__ void prep_weights(const float* __restrict__ W0, const float* __restrict__ W1,
                             short* __restrict__ W0p, short* __restrict__ W1p,
                             unsigned* __restrict__ colnz) {
    int idx = blockIdx.x * 256 + threadIdx.x;
    if (idx < NROWS) colnz[idx] = 0u;
    if (idx < NP * KP1) {
        int n = idx / KP1, kp = idx - n * KP1;
        float v = 0.f;
        if (n < MEM) {
            if (kp < 300)                   v = W0[n * IN_DIM + kp];
            else if (kp >= 304 && kp < 334) v = W0[n * IN_DIM + 300 + (kp - 304)];
            else if (kp >= 336 && kp < 366) v = W0[n * IN_DIM + 330 + (kp - 336)];
        }
        W0p[idx] = (short)f2b(v);
    } else {
        int i2 = idx - NP * KP1;
        if (i2 < NP * NP) {
            int n = i2 >> 8, k = i2 & 255;
            float v = (n < MEM && k < MEM) ? W1[n * MEM + k] : 0.f;
            W1p[i2] = (short)f2b(v);
        }
    }
}

// ---------------- adj row pass: rowsum/dinv, S = (A+I) bf16 [B][256][256], colnz flags
__global__ void adjrow_kernel(const float* __restrict__ adj, float* __restrict__ dinv,
                              float* __restrict__ rsum, unsigned short* __restrict__ Sbf,
                              unsigned* __restrict__ colnz) {
    int row = blockIdx.x * 4 + (threadIdx.x >> 6);
    int lane = threadIdx.x & 63;
    const float4* ar = (const float4*)(adj + (size_t)row * NL);
    float4 v = ar[lane];
    float s = v.x + v.y + v.z + v.w;
    #pragma unroll
    for (int off = 32; off >= 1; off >>= 1) s += __shfl_xor(s, off);
    int rloc = row & 255;
    float d0 = v.x + ((lane * 4 + 0) == rloc ? 1.f : 0.f);
    float d1 = v.y + ((lane * 4 + 1) == rloc ? 1.f : 0.f);
    float d2 = v.z + ((lane * 4 + 2) == rloc ? 1.f : 0.f);
    float d3 = v.w + ((lane * 4 + 3) == rloc ? 1.f : 0.f);
    ushort4 st; st.x = f2b(d0); st.y = f2b(d1); st.z = f2b(d2); st.w = f2b(d3);
    *(ushort4*)(Sbf + (size_t)row * NL + lane * 4) = st;
    if (lane == 0) { rsum[row] = s; dinv[row] = 1.0f / (s + 1.0f); }
    unsigned* cz = colnz + ((row >> 8) << 8);
    if (v.x != 0.f) atomicOr(&cz[lane * 4 + 0], 1u);
    if (v.y != 0.f) atomicOr(&cz[lane * 4 + 1], 1u);
    if (v.z != 0.f) atomicOr(&cz[lane * 4 + 2], 1u);
    if (v.w != 0.f) atomicOr(&cz[lane * 4 + 3], 1u);
}

// ---------------- FUSED layer 1 (r16 structure, unchanged): A-staging = embedding gather.
template <int FINAL>
__global__ __launch_bounds__(512, 4) void fused_kernel(
    const short* __restrict__ A, int lda, int nkt,
    const short* __restrict__ Bp, int ldb,
    const unsigned short* __restrict__ Sbf,
    const float* __restrict__ dinv, const float* __restrict__ bias,
    const int* __restrict__ words, const int* __restrict__ pos, const int* __restrict__ ner,
    const float* __restrict__ embW, const float* __restrict__ posW,
    const float* __restrict__ nerW,
    const float* __restrict__ rsum, const unsigned* __restrict__ colnz,
    float* __restrict__ maskout,
    short* __restrict__ x1b, float* __restrict__ outx) {
    extern __shared__ char smem[];
    unsigned short* Yt = (unsigned short*)(smem + YTOFF);   // [64][YTP] bf16

    int bi = blockIdx.x;
    int batch = bi & 127, sl = bi >> 7;                 // 4 slices of a batch -> same XCD

    int tid = threadIdx.x;
    int lane = tid & 63, wid = tid >> 6;
    int wr = wid >> 1, wc = wid & 1;                    // 4 x 2 wave grid
    int lr = lane & 15, lc = lane >> 4;

    // folded mask_kernel (FINAL=0, slice-0 blocks; adjrow outputs ready at launch)
    if (FINAL == 0 && sl == 0 && tid < 256) {
        int r = batch * NL + tid;
        maskout[r] = (rsum[r] == 0.f && colnz[r] == 0u) ? 1.0f : 0.0f;
    }

    const short* Bb = Bp + (size_t)sl * 64 * ldb;
    const short* Sb = (const short*)(Sbf + (size_t)batch * NL * NL);

    // staging slots (byte offsets within a buffer)
    int r0s = tid >> 2, c0s = tid & 3;
    int r1s = r0s + 128;
    int offA0 = r0s * 64 + (c0s ^ ((r0s >> 1) & 3)) * 16;
    int offA1 = r1s * 64 + (c0s ^ ((r1s >> 1) & 3)) * 16;
    const short* Sp0 = Sb + (size_t)r0s * NL + c0s * 8;
    const short* Sp1 = Sb + (size_t)r1s * NL + c0s * 8;
    int offB = 0; const short* Bpp = nullptr;
    if (tid < 256) {
        int br = tid >> 2, bc = tid & 3;
        offB = 16384 + br * 64 + (bc ^ ((br >> 1) & 3)) * 16;
        Bpp = Bb + (size_t)br * ldb + bc * 8;
    }

    // A source: per-row table pointers (FINAL=0 path)
    const float *er0 = nullptr, *pr0 = nullptr, *nr0 = nullptr;
    const float *er1 = nullptr, *pr1 = nullptr, *nr1 = nullptr;
    {
        int g0 = batch * NL + r0s, g1 = g0 + 128;
        er0 = embW + (size_t)words[g0] * 300;
        pr0 = posW + (size_t)pos[g0] * 30;
        nr0 = nerW + (size_t)ner[g0] * 30;
        er1 = embW + (size_t)words[g1] * 300;
        pr1 = posW + (size_t)pos[g1] * 30;
        nr1 = nerW + (size_t)ner[g1] * 30;
    }
    #define LOADA(kt, o0, o1) do {                                  \
        int ch_ = (kt) * 4 + c0s;                                   \
        (o0) = gather_chunk(ch_, er0, pr0, nr0);                    \
        (o1) = gather_chunk(ch_, er1, pr1, nr1);                    \
    } while (0)

    f32x4 acc[4][2] = {};
    // prologue: tile 0 -> buf0; load tile 1
    short8 aR0, aR1, bR;
    LOADA(0, aR0, aR1);
    if (tid < 256) bR = *(const short8*)Bpp;
    *(short8*)(smem + offA0) = aR0;
    *(short8*)(smem + offA1) = aR1;
    if (tid < 256) *(short8*)(smem + offB) = bR;
    LOADA(1, aR0, aR1);
    if (tid < 256) bR = *(const short8*)(Bpp + 32);
    __syncthreads();

    short8 sA0, sA1, sB0, sB1;                          // S t0/t1 regs
    for (int kt = 0; kt < nkt; ++kt) {
        char* base_ = smem + (kt & 1) * BUFSZ;
        short8 af[4], bf[2];
        #pragma unroll
        for (int mi = 0; mi < 4; ++mi) {
            int row = wr * 64 + mi * 16 + lr;
            int cs = lc ^ ((row >> 1) & 3);
            af[mi] = *(const short8*)(base_ + row * 64 + cs * 16);
        }
        #pragma unroll
        for (int ni = 0; ni < 2; ++ni) {
            int row = wc * 32 + ni * 16 + lr;
            int cs = lc ^ ((row >> 1) & 3);
            bf[ni] = *(const short8*)(base_ + 16384 + row * 64 + cs * 16);
        }
        if (kt + 1 < nkt) {                             // write tile kt+1 to other buffer
            char* nb_ = smem + ((kt + 1) & 1) * BUFSZ;
            *(short8*)(nb_ + offA0) = aR0;
            *(short8*)(nb_ + offA1) = aR1;
            if (tid < 256) *(short8*)(nb_ + offB) = bR;
        }
        if (kt + 2 < nkt) {                             // prefetch tile kt+2
            LOADA(kt + 2, aR0, aR1);
            if (tid < 256) bR = *(const short8*)(Bpp + (kt + 2) * 32);
        } else if (kt + 2 == nkt) {                     // tail: S t0
            sA0 = *(const short8*)Sp0;
            sA1 = *(const short8*)Sp1;
        } else if (kt + 2 == nkt + 1) {                 // tail: S t1
            sB0 = *(const short8*)(Sp0 + 32);
            sB1 = *(const short8*)(Sp1 + 32);
        }
        #pragma unroll
        for (int mi = 0; mi < 4; ++mi)
            #pragma unroll
            for (int ni = 0; ni < 2; ++ni)
                acc[mi][ni] = __builtin_amdgcn_mfma_f32_16x16x32_bf16(af[mi], bf[ni], acc[mi][ni], 0, 0, 0);
        __syncthreads();
    }
    #undef LOADA

    // Phase 2a: acc -> Yt transposed (col = y-col, 4 consecutive batch rows per 8B write)
    #pragma unroll
    for (int mi = 0; mi < 4; ++mi)
        #pragma unroll
        for (int ni = 0; ni < 2; ++ni) {
            f32x4 v = acc[mi][ni];
            ushort4 st; st.x = f2b(v[0]); st.y = f2b(v[1]); st.z = f2b(v[2]); st.w = f2b(v[3]);
            int col = wc * 32 + ni * 16 + lr;
            int row0 = wr * 64 + mi * 16 + lc * 4;
            *(ushort4*)(Yt + (size_t)col * YTP + row0) = st;
        }
    // stage S t0 -> buf0.At; prefetch t2
    *(short8*)(smem + offA0) = sA0;
    *(short8*)(smem + offA1) = sA1;
    sA0 = *(const short8*)(Sp0 + 64);
    sA1 = *(const short8*)(Sp1 + 64);
    __syncthreads();                                    // Yt + S t0 visible

    // Phase 2b: Zt = Yt x S, 8 K-tiles, ping-pong staging, 1 barrier/tile
    f32x4 acc2[4][2] = {};
    #pragma unroll
    for (int kt = 0; kt < 8; ++kt) {
        char* base_ = smem + (kt & 1) * BUFSZ;
        short8 ay[4], bs[2];
        #pragma unroll
        for (int mi = 0; mi < 4; ++mi)                  // a = Y^T rows (y-cols), k-contig
            ay[mi] = *(const short8*)(Yt + (size_t)(mi * 16 + lr) * YTP + kt * 32 + lc * 8);
        #pragma unroll
        for (int ni = 0; ni < 2; ++ni) {                // b = S rows (out-rows), swizzled
            int row = wid * 32 + ni * 16 + lr;
            int cs = lc ^ ((row >> 1) & 3);
            bs[ni] = *(const short8*)(base_ + row * 64 + cs * 16);
        }
        if (kt + 1 < 8) {                               // write tile kt+1; reload that set
            char* nb_ = smem + ((kt + 1) & 1) * BUFSZ;
            if ((kt & 1) == 0) {
                *(short8*)(nb_ + offA0) = sB0;
                *(short8*)(nb_ + offA1) = sB1;
                if (kt + 3 < 8) {
                    sB0 = *(const short8*)(Sp0 + (kt + 3) * 32);
                    sB1 = *(const short8*)(Sp1 + (kt + 3) * 32);
                }
            } else {
                *(short8*)(nb_ + offA0) = sA0;
                *(short8*)(nb_ + offA1) = sA1;
                if (kt + 3 < 8) {
                    sA0 = *(const short8*)(Sp0 + (kt + 3) * 32);
                    sA1 = *(const short8*)(Sp1 + (kt + 3) * 32);
                }
            }
        }
        #pragma unroll
        for (int mi = 0; mi < 4; ++mi)
            #pragma unroll
            for (int ni = 0; ni < 2; ++ni)
                acc2[mi][ni] = __builtin_amdgcn_mfma_f32_16x16x32_bf16(ay[mi], bs[ni], acc2[mi][ni], 0, 0, 0);
        if (kt + 1 < 8) __syncthreads();
    }

    // Epilogue: lane holds outrow lr (fixed) x 4 consecutive y-cols per frag
    #pragma unroll
    for (int ni = 0; ni < 2; ++ni) {
        int g = batch * NL + wid * 32 + ni * 16 + lr;   // global output row
        float di = dinv[g];
        #pragma unroll
        for (int mi = 0; mi < 4; ++mi) {
            int col0 = sl * 64 + mi * 16 + lc * 4;      // global col (multiple of 4)
            float4 bv;
            if (col0 < MEM) bv = *(const float4*)(bias + col0);
            else { bv.x = 0.f; bv.y = 0.f; bv.z = 0.f; bv.w = 0.f; }
            f32x4 z = acc2[mi][ni];
            float h0 = fmaxf((z[0] + 2.f * bv.x) * di, 0.f);
            float h1 = fmaxf((z[1] + 2.f * bv.y) * di, 0.f);
            float h2 = fmaxf((z[2] + 2.f * bv.z) * di, 0.f);
            float h3 = fmaxf((z[3] + 2.f * bv.w) * di, 0.f);
            ushort4 st; st.x = f2b(h0); st.y = f2b(h1); st.z = f2b(h2); st.w = f2b(h3);
            *(ushort4*)((unsigned short*)x1b + (size_t)g * NP + col0) = st;
        }
    }
}

// ---------------- FUSED layer 2: ALL staging via global_load_lds (16B), 2-phase schedule.
// LDS image identical to the reg-staged path (pre-swizzled SOURCE + linear dest = rule 21
// involution), so fragments and results are bit-identical. Phase 1/2b contain NO ds_writes
// -> raw s_barrier + vmcnt(0) per step; phase boundary uses __syncthreads (drains Yt writes).
__global__ __launch_bounds__(512, 4) void fused1_kernel(
    const short* __restrict__ A,        // X1b [32768][256] bf16
    const short* __restrict__ Bp,       // W1p [256][256] bf16
    const unsigned short* __restrict__ Sbf,
    const float* __restrict__ dinv, const float* __restrict__ bias,
    float* __restrict__ outx) {
    extern __shared__ char smem[];
    unsigned short* Yt = (unsigned short*)(smem + YTOFF);   // [64][YTP] bf16

    int bi = blockIdx.x;
    int batch = bi & 127, sl = bi >> 7;                 // 4 slices of a batch -> same XCD
    int tid = threadIdx.x;
    int lane = tid & 63, wid = tid >> 6;
    int wr = wid >> 1, wc = wid & 1;
    int lr = lane & 15, lc = lane >> 4;

    const short* Ab = A + (size_t)batch * NL * NP;
    const short* Bb = Bp + (size_t)sl * 64 * NP;
    const short* Sb = (const short*)(Sbf + (size_t)batch * NL * NL);

    // gl_lds geometry: chunk li -> row r=li>>2, cd=li&3; LDS dest = linear li*16
    // (wave-uniform base + lane*16); SOURCE col-chunk pre-swizzled: cd ^ ((r>>1)&3).
    int li0 = tid, li1 = tid + 512;
    int rA0 = li0 >> 2, cA0 = (li0 & 3) ^ ((rA0 >> 1) & 3);
    int rA1 = li1 >> 2, cA1 = (li1 & 3) ^ ((rA1 >> 1) & 3);
    const short* srcA0 = Ab + (size_t)rA0 * NP + cA0 * 8;
    const short* srcA1 = Ab + (size_t)rA1 * NP + cA1 * 8;
    const short* srcS0 = Sb + (size_t)rA0 * NL + cA0 * 8;
    const short* srcS1 = Sb + (size_t)rA1 * NL + cA1 * 8;
    const short* srcB = nullptr;
    if (wid < 4) {
        int rB = tid >> 2, cB = (tid & 3) ^ ((rB >> 1) & 3);
        srcB = Bb + (size_t)rB * NP + cB * 8;
    }
    // wave-uniform LDS dest bases (HW adds lane*16)
    int dA0 = (wid * 64) * 16;
    int dA1 = (512 + wid * 64) * 16;
    int dB  = 16384 + (wid * 64) * 16;

    #define STAGE1(b, kt) do {                                       \
        char* bb_ = smem + (b) * BUFSZ;                              \
        gl16(srcA0 + (kt) * 32, bb_ + dA0);                          \
        gl16(srcA1 + (kt) * 32, bb_ + dA1);                          \
        if (wid < 4) gl16(srcB + (kt) * 32, bb_ + dB);               \
    } while (0)
    #define STAGES(b, kt) do {                                       \
        char* bb_ = smem + (b) * BUFSZ;                              \
        gl16(srcS0 + (kt) * 32, bb_ + dA0);                          \
        gl16(srcS1 + (kt) * 32, bb_ + dA1);                         \
    } while (0)
    #define WAITBAR() do {                                           \
        asm volatile("s_waitcnt vmcnt(0)" ::: "memory");             \
        __builtin_amdgcn_sched_barrier(0);                           \
        __builtin_amdgcn_s_barrier();                                \
    } while (0)

    f32x4 acc[4][2] = {};
    STAGE1(0, 0);
    WAITBAR();
    #pragma unroll
    for (int kt = 0; kt < 8; ++kt) {                    // K=256, BK=32
        if (kt + 1 < 8) STAGE1((kt + 1) & 1, kt + 1);   // issue next tile first
        char* base_ = smem + (kt & 1) * BUFSZ;
        short8 af[4], bf[2];
        #pragma unroll
        for (int mi = 0; mi < 4; ++mi) {
            int row = wr * 64 + mi * 16 + lr;
            int cs = lc ^ ((row >> 1) & 3);
            af[mi] = *(const short8*)(base_ + row * 64 + cs * 16);
        }
        #pragma unroll
        for (int ni = 0; ni < 2; ++ni) {
            int row = wc * 32 + ni * 16 + lr;
            int cs = lc ^ ((row >> 1) & 3);
            bf[ni] = *(const short8*)(base_ + 16384 + row * 64 + cs * 16);
        }
        #pragma unroll
        for (int mi = 0; mi < 4; ++mi)
            #pragma unroll
            for (int ni = 0; ni < 2; ++ni)
                acc[mi][ni] = __builtin_amdgcn_mfma_f32_16x16x32_bf16(af[mi], bf[ni], acc[mi][ni], 0, 0, 0);
        WAITBAR();                                      // next tile in LDS + reads done
    }

    // Phase 2a: issue S tile 0 early, write Yt, drain everything
    STAGES(0, 0);
    #pragma unroll
    for (int mi = 0; mi < 4; ++mi)
        #pragma unroll
        for (int ni = 0; ni < 2; ++ni) {
            f32x4 v = acc[mi][ni];
            ushort4 st; st.x = f2b(v[0]); st.y = f2b(v[1]); st.z = f2b(v[2]); st.w = f2b(v[3]);
            int col = wc * 32 + ni * 16 + lr;
            int row0 = wr * 64 + mi * 16 + lc * 4;
            *(ushort4*)(Yt + (size_t)col * YTP + row0) = st;
        }
    asm volatile("s_waitcnt vmcnt(0)" ::: "memory");
    __builtin_amdgcn_sched_barrier(0);
    __syncthreads();                                    // drains lgkm (Yt) + barrier

    // Phase 2b: Zt = Yt x S, 8 K-tiles, gl_lds ping-pong, 1 barrier/tile
    f32x4 acc2[4][2] = {};
    #pragma unroll
    for (int kt = 0; kt < 8; ++kt) {
        if (kt + 1 < 8) STAGES((kt + 1) & 1, kt + 1);
        char* base_ = smem + (kt & 1) * BUFSZ;
        short8 ay[4], bs[2];
        #pragma unroll
        for (int mi = 0; mi < 4; ++mi)
            ay[mi] = *(const short8*)(Yt + (size_t)(mi * 16 + lr) * YTP + kt * 32 + lc * 8);
        #pragma unroll
        for (int ni = 0; ni < 2; ++ni) {
            int row = wid * 32 + ni * 16 + lr;
            int cs = lc ^ ((row >> 1) & 3);
            bs[ni] = *(const short8*)(base_ + row * 64 + cs * 16);
        }
        #pragma unroll
        for (int mi = 0; mi < 4; ++mi)
            #pragma unroll
            for (int ni = 0; ni < 2; ++ni)
                acc2[mi][ni] = __builtin_amdgcn_mfma_f32_16x16x32_bf16(ay[mi], bs[ni], acc2[mi][ni], 0, 0, 0);
        if (kt + 1 < 8) WAITBAR();
    }
    #undef STAGE1
    #undef STAGES
    #undef WAITBAR

    // Epilogue: f32 out [32768][200]
    #pragma unroll
    for (int ni = 0; ni < 2; ++ni) {
        int g = batch * NL + wid * 32 + ni * 16 + lr;
        float di = dinv[g];
        #pragma unroll
        for (int mi = 0; mi < 4; ++mi) {
            int col0 = sl * 64 + mi * 16 + lc * 4;
            if (col0 < MEM) {
                float4 bv = *(const float4*)(bias + col0);
                f32x4 z = acc2[mi][ni];
                float4 o;
                o.x = fmaxf((z[0] + 2.f * bv.x) * di, 0.f);
                o.y = fmaxf((z[1] + 2.f * bv.y) * di, 0.f);
                o.z = fmaxf((z[2] + 2.f * bv.z) * di, 0.f);
                o.w = fmaxf((z[3] + 2.f * bv.w) * di, 0.f);
                *(float4*)(outx + (size_t)g * MEM + col0) = o;
            }
        }
    }
}

extern "C" void kernel_launch(void* const* d_in, const int* in_sizes, int n_in,
                              void* d_out, int out_size, void* d_ws, size_t ws_size,
                              hipStream_t stream) {
    const int*   words = (const int*)d_in[0];
    const int*   pos   = (const int*)d_in[1];
    const int*   ner   = (const int*)d_in[2];
    const float* adj   = (const float*)d_in[3];
    const float* embW  = (const float*)d_in[4];
    const float* posW  = (const float*)d_in[5];
    const float* nerW  = (const float*)d_in[6];
    const float* W0    = (const float*)d_in[7];
    const float* b0    = (const float*)d_in[8];
    const float* W1    = (const float*)d_in[9];
    const float* b1    = (const float*)d_in[10];
    float* out = (float*)d_out;

    char* ws = (char*)d_ws;
    size_t off = 0;
    short* W0p = (short*)(ws + off);        off += (size_t)NP * KP1 * 2;
    short* W1p = (short*)(ws + off);        off += (size_t)NP * NP * 2;
    short* X1b = (short*)(ws + off);        off += (size_t)NROWS * NP * 2;        // 16.8 MB
    float* dinv = (float*)(ws + off);       off += (size_t)NROWS * 4;
    float* rsum = (float*)(ws + off);       off += (size_t)NROWS * 4;
    unsigned* colnz = (unsigned*)(ws + off); off += (size_t)NROWS * 4;
    unsigned short* Sbf = (unsigned short*)(ws + off); off += (size_t)NROWS * NL * 2; // 16.8 MB

    prep_weights<<<(NP * KP1 + NP * NP + 255) / 256, 256, 0, stream>>>(W0, W1, W0p, W1p, colnz);
    adjrow_kernel<<<NROWS / 4, 256, 0, stream>>>(adj, dinv, rsum, Sbf, colnz);

    const int ldsB = YTOFF + 64 * YTP * 2;   // 74,752 B
    fused_kernel<0><<<NB * 4, 512, ldsB, stream>>>(nullptr, KP1, KP1 / 32, W0p, KP1,
                                                   Sbf, dinv, b0,
                                                   words, pos, ner, embW, posW, nerW,
                                                   rsum, colnz, out + OUT_X,
                                                   X1b, nullptr);
    fused1_kernel<<<NB * 4, 512, ldsB, stream>>>(X1b, W1p, Sbf, dinv, b1, out);
}

// Round 19
// 67.509 us; speedup vs baseline: 1.2780x; 1.2042x over previous
//
#include <hip/hip_runtime.h>
#include <hip/hip_bf16.h>
#include <stdint.h>

typedef __attribute__((ext_vector_type(8))) short short8;
typedef __attribute__((ext_vector_type(4))) float f32x4;

#define NB 128
#define NL 256
#define NROWS 32768        // B*L
#define IN_DIM 360
#define KP1 384            // padded K for layer-1 GEMM (permuted layout)
#define MEM 200
#define NP 256             // padded N
#define OUT_X (NROWS * MEM)
#define YTP 264            // Yt pitch in bf16 (528 B rows)
#define BUFSZ 20480        // one staging buffer: At 16K + Bt 4K
#define YTOFF 40960        // Yt offset in smem
#define RSOFF 74752        // dinvL[256] f32 + colnzL[8] u32 (fused0 only)

// Permuted K layout for x/W0p: kp 0..299 emb | 304..333 pos | 336..365 ner | else zero

__device__ __forceinline__ unsigned short f2b(float f) {
    unsigned u = __builtin_bit_cast(unsigned, f);
    unsigned r = (u + 0x7FFFu + ((u >> 16) & 1u)) >> 16;
    return (unsigned short)r;
}

__device__ __forceinline__ void gl16(const void* g, void* l) {
    __builtin_amdgcn_global_load_lds((const __attribute__((address_space(1))) unsigned*)g,
                                     (__attribute__((address_space(3))) unsigned*)l, 16, 0, 0);
}

// gather one 8-col chunk of the (permuted) embedding row as bf16
__device__ __forceinline__ short8 gather_chunk(int chunk, const float* __restrict__ er,
                                               const float* __restrict__ pr,
                                               const float* __restrict__ nr) {
    float v[8];
    if (chunk < 37) {
        const float* s = er + chunk * 8;
        float4 a = *(const float4*)s;
        float4 b = *(const float4*)(s + 4);
        v[0] = a.x; v[1] = a.y; v[2] = a.z; v[3] = a.w;
        v[4] = b.x; v[5] = b.y; v[6] = b.z; v[7] = b.w;
    } else if (chunk == 37) {
        float4 a = *(const float4*)(er + 296);
        v[0] = a.x; v[1] = a.y; v[2] = a.z; v[3] = a.w;
        v[4] = 0.f; v[5] = 0.f; v[6] = 0.f; v[7] = 0.f;
    } else if (chunk <= 41) {
        int k0 = chunk * 8 - 304;
        #pragma unroll
        for (int i = 0; i < 8; ++i) v[i] = (k0 + i < 30) ? pr[k0 + i] : 0.f;
    } else if (chunk <= 45) {
        int k0 = chunk * 8 - 336;
        #pragma unroll
        for (int i = 0; i < 8; ++i) v[i] = (k0 + i < 30) ? nr[k0 + i] : 0.f;
    } else {
        #pragma unroll
        for (int i = 0; i < 8; ++i) v[i] = 0.f;
    }
    short8 r;
    #pragma unroll
    for (int i = 0; i < 8; ++i) r[i] = (short)f2b(v[i]);
    return r;
}

// ---------------- weight prep
__global__ void prep_weights(const float* __restrict__ W0, const float* __restrict__ W1,
                             short* __restrict__ W0p, short* __restrict__ W1p) {
    int idx = blockIdx.x * 256 + threadIdx.x;
    if (idx < NP * KP1) {
        int n = idx / KP1, kp = idx - n * KP1;
        float v = 0.f;
        if (n < MEM) {
            if (kp < 300)                   v = W0[n * IN_DIM + kp];
            else if (kp >= 304 && kp < 334) v = W0[n * IN_DIM + 300 + (kp - 304)];
            else if (kp >= 336 && kp < 366) v = W0[n * IN_DIM + 330 + (kp - 336)];
        }
        W0p[idx] = (short)f2b(v);
    } else {
        int i2 = idx - NP * KP1;
        if (i2 < NP * NP) {
            int n = i2 >> 8, k = i2 & 255;
            float v = (n < MEM && k < MEM) ? W1[n * MEM + k] : 0.f;
            W1p[i2] = (short)f2b(v);
        }
    }
}

// ---------------- FUSED layer 1 + adjacency pre-phase (adjrow absorbed).
// Pre-phase: stream batch adj panel (256 KB, coalesced); emit S=(A+I) bf16 -> Sbf
// (all 4 sibling blocks write identical values: race-free), row sums -> dinvL (LDS),
// colnz bits -> mask (sl==0 writes mask + dinv global for layer 2).
// Then r16 structure: phase1 dbuf GEMM (A = embedding gather), phase2a Yt, phase2b Zt=Yt*S.
__global__ __launch_bounds__(512, 4) void fused0_kernel(
    const short* __restrict__ Bp,
    unsigned short* __restrict__ Sbf,
    const float* __restrict__ bias,
    const int* __restrict__ words, const int* __restrict__ pos, const int* __restrict__ ner,
    const float* __restrict__ embW, const float* __restrict__ posW,
    const float* __restrict__ nerW,
    const float* __restrict__ adj,
    float* __restrict__ maskout, float* __restrict__ dinvg,
    short* __restrict__ x1b) {
    extern __shared__ char smem[];
    unsigned short* Yt = (unsigned short*)(smem + YTOFF);   // [64][YTP] bf16
    float* dinvL = (float*)(smem + RSOFF);                  // [256]
    unsigned* colnzL = (unsigned*)(smem + RSOFF + 1024);    // [8]

    int bi = blockIdx.x;
    int batch = bi & 127, sl = bi >> 7;                 // 4 slices of a batch -> same XCD
    int tid = threadIdx.x;
    int lane = tid & 63, wid = tid >> 6;
    int wr = wid >> 1, wc = wid & 1;
    int lr = lane & 15, lc = lane >> 4;

    // ---- pre-phase: adj panel -> S panel + rowsum/colnz
    if (tid < 256) dinvL[tid] = 0.f;                    // rowsum accumulator first
    if (tid < 8) colnzL[tid] = 0u;
    __syncthreads();
    {
        const float* adjb = adj + (size_t)batch * NL * NL;
        unsigned short* Sw = Sbf + (size_t)batch * NL * NL;
        #pragma unroll 4
        for (int j = 0; j < 16; ++j) {
            int cidx = j * 512 + tid;                   // 8-elem chunk, 8192 total
            int r = cidx >> 5, c0 = (cidx & 31) << 3;
            const float* src = adjb + (size_t)r * NL + c0;
            float4 a = *(const float4*)src;
            float4 b = *(const float4*)(src + 4);
            float s8 = a.x + a.y + a.z + a.w + b.x + b.y + b.z + b.w;
            unsigned bits = 0;
            bits |= (a.x != 0.f) ? 1u : 0u;   bits |= (a.y != 0.f) ? 2u : 0u;
            bits |= (a.z != 0.f) ? 4u : 0u;   bits |= (a.w != 0.f) ? 8u : 0u;
            bits |= (b.x != 0.f) ? 16u : 0u;  bits |= (b.y != 0.f) ? 32u : 0u;
            bits |= (b.z != 0.f) ? 64u : 0u;  bits |= (b.w != 0.f) ? 128u : 0u;
            // 32 contiguous lanes share row r: reduce within the 32-group
            #pragma unroll
            for (int o = 16; o >= 1; o >>= 1) s8 += __shfl_xor(s8, o);
            if ((lane & 31) == 0) atomicAdd(&dinvL[r], s8);
            if (bits) atomicOr(&colnzL[c0 >> 5], bits << (c0 & 31));
            // diag add (+I), convert, store (coalesced 16B/lane)
            float d0 = a.x + ((c0 + 0 == r) ? 1.f : 0.f);
            float d1 = a.y + ((c0 + 1 == r) ? 1.f : 0.f);
            float d2 = a.z + ((c0 + 2 == r) ? 1.f : 0.f);
            float d3 = a.w + ((c0 + 3 == r) ? 1.f : 0.f);
            float d4 = b.x + ((c0 + 4 == r) ? 1.f : 0.f);
            float d5 = b.y + ((c0 + 5 == r) ? 1.f : 0.f);
            float d6 = b.z + ((c0 + 6 == r) ? 1.f : 0.f);
            float d7 = b.w + ((c0 + 7 == r) ? 1.f : 0.f);
            short8 st;
            st[0] = (short)f2b(d0); st[1] = (short)f2b(d1);
            st[2] = (short)f2b(d2); st[3] = (short)f2b(d3);
            st[4] = (short)f2b(d4); st[5] = (short)f2b(d5);
            st[6] = (short)f2b(d6); st[7] = (short)f2b(d7);
            *(short8*)(Sw + (size_t)r * NL + c0) = st;
        }
    }
    __syncthreads();                                    // sums/bits final; Sbf writes drained
    if (tid < 256) {
        float s = dinvL[tid];
        float di = 1.0f / (s + 1.0f);
        dinvL[tid] = di;                                // repurpose as dinv
        if (sl == 0) {
            unsigned bit = (colnzL[tid >> 5] >> (tid & 31)) & 1u;
            maskout[batch * NL + tid] = (s == 0.f && bit == 0u) ? 1.0f : 0.0f;
            dinvg[batch * NL + tid] = di;               // for layer 2
        }
    }

    const short* Bb = Bp + (size_t)sl * 64 * KP1;
    const short* Sb = (const short*)(Sbf + (size_t)batch * NL * NL);

    // staging slots (byte offsets within a buffer)
    int r0s = tid >> 2, c0s = tid & 3;
    int r1s = r0s + 128;
    int offA0 = r0s * 64 + (c0s ^ ((r0s >> 1) & 3)) * 16;
    int offA1 = r1s * 64 + (c0s ^ ((r1s >> 1) & 3)) * 16;
    const short* Sp0 = Sb + (size_t)r0s * NL + c0s * 8;
    const short* Sp1 = Sb + (size_t)r1s * NL + c0s * 8;
    int offB = 0; const short* Bpp = nullptr;
    if (tid < 256) {
        int br = tid >> 2, bc = tid & 3;
        offB = 16384 + br * 64 + (bc ^ ((br >> 1) & 3)) * 16;
        Bpp = Bb + (size_t)br * KP1 + bc * 8;
    }

    // A source: per-row embedding table pointers
    const float *er0, *pr0, *nr0, *er1, *pr1, *nr1;
    {
        int g0 = batch * NL + r0s, g1 = g0 + 128;
        er0 = embW + (size_t)words[g0] * 300;
        pr0 = posW + (size_t)pos[g0] * 30;
        nr0 = nerW + (size_t)ner[g0] * 30;
        er1 = embW + (size_t)words[g1] * 300;
        pr1 = posW + (size_t)pos[g1] * 30;
        nr1 = nerW + (size_t)ner[g1] * 30;
    }
    #define LOADA(kt, o0, o1) do {                                  \
        int ch_ = (kt) * 4 + c0s;                                   \
        (o0) = gather_chunk(ch_, er0, pr0, nr0);                    \
        (o1) = gather_chunk(ch_, er1, pr1, nr1);                    \
    } while (0)

    f32x4 acc[4][2] = {};
    short8 aR0, aR1, bR;
    LOADA(0, aR0, aR1);
    if (tid < 256) bR = *(const short8*)Bpp;
    *(short8*)(smem + offA0) = aR0;
    *(short8*)(smem + offA1) = aR1;
    if (tid < 256) *(short8*)(smem + offB) = bR;
    LOADA(1, aR0, aR1);
    if (tid < 256) bR = *(const short8*)(Bpp + 32);
    __syncthreads();

    short8 sA0, sA1, sB0, sB1;
    const int nkt = KP1 / 32;                           // 12
    for (int kt = 0; kt < nkt; ++kt) {
        char* base_ = smem + (kt & 1) * BUFSZ;
        short8 af[4], bf[2];
        #pragma unroll
        for (int mi = 0; mi < 4; ++mi) {
            int row = wr * 64 + mi * 16 + lr;
            int cs = lc ^ ((row >> 1) & 3);
            af[mi] = *(const short8*)(base_ + row * 64 + cs * 16);
        }
        #pragma unroll
        for (int ni = 0; ni < 2; ++ni) {
            int row = wc * 32 + ni * 16 + lr;
            int cs = lc ^ ((row >> 1) & 3);
            bf[ni] = *(const short8*)(base_ + 16384 + row * 64 + cs * 16);
        }
        if (kt + 1 < nkt) {
            char* nb_ = smem + ((kt + 1) & 1) * BUFSZ;
            *(short8*)(nb_ + offA0) = aR0;
            *(short8*)(nb_ + offA1) = aR1;
            if (tid < 256) *(short8*)(nb_ + offB) = bR;
        }
        if (kt + 2 < nkt) {
            LOADA(kt + 2, aR0, aR1);
            if (tid < 256) bR = *(const short8*)(Bpp + (kt + 2) * 32);
        } else if (kt + 2 == nkt) {
            sA0 = *(const short8*)Sp0;
            sA1 = *(const short8*)Sp1;
        } else if (kt + 2 == nkt + 1) {
            sB0 = *(const short8*)(Sp0 + 32);
            sB1 = *(const short8*)(Sp1 + 32);
        }
        #pragma unroll
        for (int mi = 0; mi < 4; ++mi)
            #pragma unroll
            for (int ni = 0; ni < 2; ++ni)
                acc[mi][ni] = __builtin_amdgcn_mfma_f32_16x16x32_bf16(af[mi], bf[ni], acc[mi][ni], 0, 0, 0);
        __syncthreads();
    }
    #undef LOADA

    // Phase 2a: acc -> Yt transposed
    #pragma unroll
    for (int mi = 0; mi < 4; ++mi)
        #pragma unroll
        for (int ni = 0; ni < 2; ++ni) {
            f32x4 v = acc[mi][ni];
            ushort4 st; st.x = f2b(v[0]); st.y = f2b(v[1]); st.z = f2b(v[2]); st.w = f2b(v[3]);
            int col = wc * 32 + ni * 16 + lr;
            int row0 = wr * 64 + mi * 16 + lc * 4;
            *(ushort4*)(Yt + (size_t)col * YTP + row0) = st;
        }
    *(short8*)(smem + offA0) = sA0;
    *(short8*)(smem + offA1) = sA1;
    sA0 = *(const short8*)(Sp0 + 64);
    sA1 = *(const short8*)(Sp1 + 64);
    __syncthreads();

    // Phase 2b: Zt = Yt x S, 8 K-tiles, ping-pong staging
    f32x4 acc2[4][2] = {};
    #pragma unroll
    for (int kt = 0; kt < 8; ++kt) {
        char* base_ = smem + (kt & 1) * BUFSZ;
        short8 ay[4], bs[2];
        #pragma unroll
        for (int mi = 0; mi < 4; ++mi)
            ay[mi] = *(const short8*)(Yt + (size_t)(mi * 16 + lr) * YTP + kt * 32 + lc * 8);
        #pragma unroll
        for (int ni = 0; ni < 2; ++ni) {
            int row = wid * 32 + ni * 16 + lr;
            int cs = lc ^ ((row >> 1) & 3);
            bs[ni] = *(const short8*)(base_ + row * 64 + cs * 16);
        }
        if (kt + 1 < 8) {
            char* nb_ = smem + ((kt + 1) & 1) * BUFSZ;
            if ((kt & 1) == 0) {
                *(short8*)(nb_ + offA0) = sB0;
                *(short8*)(nb_ + offA1) = sB1;
                if (kt + 3 < 8) {
                    sB0 = *(const short8*)(Sp0 + (kt + 3) * 32);
                    sB1 = *(const short8*)(Sp1 + (kt + 3) * 32);
                }
            } else {
                *(short8*)(nb_ + offA0) = sA0;
                *(short8*)(nb_ + offA1) = sA1;
                if (kt + 3 < 8) {
                    sA0 = *(const short8*)(Sp0 + (kt + 3) * 32);
                    sA1 = *(const short8*)(Sp1 + (kt + 3) * 32);
                }
            }
        }
        #pragma unroll
        for (int mi = 0; mi < 4; ++mi)
            #pragma unroll
            for (int ni = 0; ni < 2; ++ni)
                acc2[mi][ni] = __builtin_amdgcn_mfma_f32_16x16x32_bf16(ay[mi], bs[ni], acc2[mi][ni], 0, 0, 0);
        if (kt + 1 < 8) __syncthreads();
    }

    // Epilogue: dinv from LDS
    #pragma unroll
    for (int ni = 0; ni < 2; ++ni) {
        int rloc = wid * 32 + ni * 16 + lr;
        int g = batch * NL + rloc;
        float di = dinvL[rloc];
        #pragma unroll
        for (int mi = 0; mi < 4; ++mi) {
            int col0 = sl * 64 + mi * 16 + lc * 4;
            float4 bv;
            if (col0 < MEM) bv = *(const float4*)(bias + col0);
            else { bv.x = 0.f; bv.y = 0.f; bv.z = 0.f; bv.w = 0.f; }
            f32x4 z = acc2[mi][ni];
            ushort4 st;
            st.x = f2b(fmaxf((z[0] + 2.f * bv.x) * di, 0.f));
            st.y = f2b(fmaxf((z[1] + 2.f * bv.y) * di, 0.f));
            st.z = f2b(fmaxf((z[2] + 2.f * bv.z) * di, 0.f));
            st.w = f2b(fmaxf((z[3] + 2.f * bv.w) * di, 0.f));
            *(ushort4*)((unsigned short*)x1b + (size_t)g * NP + col0) = st;
        }
    }
}

// ---------------- FUSED layer 2: all staging via global_load_lds (r18 structure, unchanged)
__global__ __launch_bounds__(512, 4) void fused1_kernel(
    const short* __restrict__ A,        // X1b [32768][256] bf16
    const short* __restrict__ Bp,       // W1p [256][256] bf16
    const unsigned short* __restrict__ Sbf,
    const float* __restrict__ dinv, const float* __restrict__ bias,
    float* __restrict__ outx) {
    extern __shared__ char smem[];
    unsigned short* Yt = (unsigned short*)(smem + YTOFF);

    int bi = blockIdx.x;
    int batch = bi & 127, sl = bi >> 7;
    int tid = threadIdx.x;
    int lane = tid & 63, wid = tid >> 6;
    int wr = wid >> 1, wc = wid & 1;
    int lr = lane & 15, lc = lane >> 4;

    const short* Ab = A + (size_t)batch * NL * NP;
    const short* Bb = Bp + (size_t)sl * 64 * NP;
    const short* Sb = (const short*)(Sbf + (size_t)batch * NL * NL);

    int li0 = tid, li1 = tid + 512;
    int rA0 = li0 >> 2, cA0 = (li0 & 3) ^ ((rA0 >> 1) & 3);
    int rA1 = li1 >> 2, cA1 = (li1 & 3) ^ ((rA1 >> 1) & 3);
    const short* srcA0 = Ab + (size_t)rA0 * NP + cA0 * 8;
    const short* srcA1 = Ab + (size_t)rA1 * NP + cA1 * 8;
    const short* srcS0 = Sb + (size_t)rA0 * NL + cA0 * 8;
    const short* srcS1 = Sb + (size_t)rA1 * NL + cA1 * 8;
    const short* srcB = nullptr;
    if (wid < 4) {
        int rB = tid >> 2, cB = (tid & 3) ^ ((rB >> 1) & 3);
        srcB = Bb + (size_t)rB * NP + cB * 8;
    }
    int dA0 = (wid * 64) * 16;
    int dA1 = (512 + wid * 64) * 16;
    int dB  = 16384 + (wid * 64) * 16;

    #define STAGE1(b, kt) do {                                       \
        char* bb_ = smem + (b) * BUFSZ;                              \
        gl16(srcA0 + (kt) * 32, bb_ + dA0);                          \
        gl16(srcA1 + (kt) * 32, bb_ + dA1);                          \
        if (wid < 4) gl16(srcB + (kt) * 32, bb_ + dB);               \
    } while (0)
    #define STAGES(b, kt) do {                                       \
        char* bb_ = smem + (b) * BUFSZ;                              \
        gl16(srcS0 + (kt) * 32, bb_ + dA0);                          \
        gl16(srcS1 + (kt) * 32, bb_ + dA1);                          \
    } while (0)
    #define WAITBAR() do {                                           \
        asm volatile("s_waitcnt vmcnt(0)" ::: "memory");             \
        __builtin_amdgcn_sched_barrier(0);                           \
        __builtin_amdgcn_s_barrier();                                \
    } while (0)

    f32x4 acc[4][2] = {};
    STAGE1(0, 0);
    WAITBAR();
    #pragma unroll
    for (int kt = 0; kt < 8; ++kt) {
        if (kt + 1 < 8) STAGE1((kt + 1) & 1, kt + 1);
        char* base_ = smem + (kt & 1) * BUFSZ;
        short8 af[4], bf[2];
        #pragma unroll
        for (int mi = 0; mi < 4; ++mi) {
            int row = wr * 64 + mi * 16 + lr;
            int cs = lc ^ ((row >> 1) & 3);
            af[mi] = *(const short8*)(base_ + row * 64 + cs * 16);
        }
        #pragma unroll
        for (int ni = 0; ni < 2; ++ni) {
            int row = wc * 32 + ni * 16 + lr;
            int cs = lc ^ ((row >> 1) & 3);
            bf[ni] = *(const short8*)(base_ + 16384 + row * 64 + cs * 16);
        }
        #pragma unroll
        for (int mi = 0; mi < 4; ++mi)
            #pragma unroll
            for (int ni = 0; ni < 2; ++ni)
                acc[mi][ni] = __builtin_amdgcn_mfma_f32_16x16x32_bf16(af[mi], bf[ni], acc[mi][ni], 0, 0, 0);
        WAITBAR();
    }

    STAGES(0, 0);
    #pragma unroll
    for (int mi = 0; mi < 4; ++mi)
        #pragma unroll
        for (int ni = 0; ni < 2; ++ni) {
            f32x4 v = acc[mi][ni];
            ushort4 st; st.x = f2b(v[0]); st.y = f2b(v[1]); st.z = f2b(v[2]); st.w = f2b(v[3]);
            int col = wc * 32 + ni * 16 + lr;
            int row0 = wr * 64 + mi * 16 + lc * 4;
            *(ushort4*)(Yt + (size_t)col * YTP + row0) = st;
        }
    asm volatile("s_waitcnt vmcnt(0)" ::: "memory");
    __builtin_amdgcn_sched_barrier(0);
    __syncthreads();

    f32x4 acc2[4][2] = {};
    #pragma unroll
    for (int kt = 0; kt < 8; ++kt) {
        if (kt + 1 < 8) STAGES((kt + 1) & 1, kt + 1);
        char* base_ = smem + (kt & 1) * BUFSZ;
        short8 ay[4], bs[2];
        #pragma unroll
        for (int mi = 0; mi < 4; ++mi)
            ay[mi] = *(const short8*)(Yt + (size_t)(mi * 16 + lr) * YTP + kt * 32 + lc * 8);
        #pragma unroll
        for (int ni = 0; ni < 2; ++ni) {
            int row = wid * 32 + ni * 16 + lr;
            int cs = lc ^ ((row >> 1) & 3);
            bs[ni] = *(const short8*)(base_ + row * 64 + cs * 16);
        }
        #pragma unroll
        for (int mi = 0; mi < 4; ++mi)
            #pragma unroll
            for (int ni = 0; ni < 2; ++ni)
                acc2[mi][ni] = __builtin_amdgcn_mfma_f32_16x16x32_bf16(ay[mi], bs[ni], acc2[mi][ni], 0, 0, 0);
        if (kt + 1 < 8) WAITBAR();
    }
    #undef STAGE1
    #undef STAGES
    #undef WAITBAR

    #pragma unroll
    for (int ni = 0; ni < 2; ++ni) {
        int g = batch * NL + wid * 32 + ni * 16 + lr;
        float di = dinv[g];
        #pragma unroll
        for (int mi = 0; mi < 4; ++mi) {
            int col0 = sl * 64 + mi * 16 + lc * 4;
            if (col0 < MEM) {
                float4 bv = *(const float4*)(bias + col0);
                f32x4 z = acc2[mi][ni];
                float4 o;
                o.x = fmaxf((z[0] + 2.f * bv.x) * di, 0.f);
                o.y = fmaxf((z[1] + 2.f * bv.y) * di, 0.f);
                o.z = fmaxf((z[2] + 2.f * bv.z) * di, 0.f);
                o.w = fmaxf((z[3] + 2.f * bv.w) * di, 0.f);
                *(float4*)(outx + (size_t)g * MEM + col0) = o;
            }
        }
    }
}

extern "C" void kernel_launch(void* const* d_in, const int* in_sizes, int n_in,
                              void* d_out, int out_size, void* d_ws, size_t ws_size,
                              hipStream_t stream) {
    const int*   words = (const int*)d_in[0];
    const int*   pos   = (const int*)d_in[1];
    const int*   ner   = (const int*)d_in[2];
    const float* adj   = (const float*)d_in[3];
    const float* embW  = (const float*)d_in[4];
    const float* posW  = (const float*)d_in[5];
    const float* nerW  = (const float*)d_in[6];
    const float* W0    = (const float*)d_in[7];
    const float* b0    = (const float*)d_in[8];
    const float* W1    = (const float*)d_in[9];
    const float* b1    = (const float*)d_in[10];
    float* out = (float*)d_out;

    char* ws = (char*)d_ws;
    size_t off = 0;
    short* W0p = (short*)(ws + off);        off += (size_t)NP * KP1 * 2;
    short* W1p = (short*)(ws + off);        off += (size_t)NP * NP * 2;
    short* X1b = (short*)(ws + off);        off += (size_t)NROWS * NP * 2;        // 16.8 MB
    float* dinv = (float*)(ws + off);       off += (size_t)NROWS * 4;
    unsigned short* Sbf = (unsigned short*)(ws + off); off += (size_t)NROWS * NL * 2; // 16.8 MB

    prep_weights<<<(NP * KP1 + NP * NP + 255) / 256, 256, 0, stream>>>(W0, W1, W0p, W1p);

    const int ldsB0 = RSOFF + 1024 + 32;     // 75,808 B
    const int ldsB1 = YTOFF + 64 * YTP * 2;  // 74,752 B
    fused0_kernel<<<NB * 4, 512, ldsB0, stream>>>(W0p, Sbf, b0,
                                                  words, pos, ner, embW, posW, nerW,
                                                  adj, out + OUT_X, dinv, X1b);
    fused1_kernel<<<NB * 4, 512, ldsB1, stream>>>(X1b, W1p, Sbf, dinv, b1, out);
}